// Round 1
// baseline (426.781 us; speedup 1.0000x reference)
//
#include <hip/hip_runtime.h>

using short8 = __attribute__((ext_vector_type(8))) short;          // 8 bf16 (4 VGPR)
using f32x4  = __attribute__((ext_vector_type(4))) float;          // MFMA acc
using u16x4  = __attribute__((ext_vector_type(4))) unsigned short; // 8B bf16 store

#define AS1 __attribute__((address_space(1)))
#define AS3 __attribute__((address_space(3)))

__device__ __forceinline__ unsigned short f2bf(float f) {
    unsigned u = __builtin_bit_cast(unsigned, f);
    u += 0x7fffu + ((u >> 16) & 1u);           // RNE
    return (unsigned short)(u >> 16);
}

// ---------------------------------------------------------------- LN -> bf16
__global__ __launch_bounds__(256) void ln_to_bf16(
    const float* __restrict__ X, const float* __restrict__ gw,
    const float* __restrict__ bw, unsigned short* __restrict__ Y)
{
    const int row = blockIdx.x;
    const int tid = threadIdx.x;
    const float4 v = *(const float4*)(X + (size_t)row * 1024 + tid * 4);
    float s  = v.x + v.y + v.z + v.w;
    float s2 = v.x*v.x + v.y*v.y + v.z*v.z + v.w*v.w;
    #pragma unroll
    for (int off = 1; off < 64; off <<= 1) {
        s  += __shfl_xor(s,  off);
        s2 += __shfl_xor(s2, off);
    }
    __shared__ float rs[4], rq[4];
    if ((tid & 63) == 0) { rs[tid >> 6] = s; rq[tid >> 6] = s2; }
    __syncthreads();
    s  = rs[0] + rs[1] + rs[2] + rs[3];
    s2 = rq[0] + rq[1] + rq[2] + rq[3];
    const float mean = s * (1.f / 1024.f);
    const float var  = s2 * (1.f / 1024.f) - mean * mean;
    const float rstd = rsqrtf(var + 1e-5f);
    const float4 gv = *(const float4*)(gw + tid * 4);
    const float4 bv = *(const float4*)(bw + tid * 4);
    u16x4 o;
    o[0] = f2bf((v.x - mean) * rstd * gv.x + bv.x);
    o[1] = f2bf((v.y - mean) * rstd * gv.y + bv.y);
    o[2] = f2bf((v.z - mean) * rstd * gv.z + bv.z);
    o[3] = f2bf((v.w - mean) * rstd * gv.w + bv.w);
    *(u16x4*)(Y + (size_t)row * 1024 + tid * 4) = o;
}

// ---------------------------------------------------------------- f32 -> bf16
__global__ __launch_bounds__(256) void cast_bf16(
    const float* __restrict__ X, unsigned short* __restrict__ Y, int n4)
{
    int i = blockIdx.x * 256 + threadIdx.x;
    if (i >= n4) return;
    float4 v = ((const float4*)X)[i];
    u16x4 o = { f2bf(v.x), f2bf(v.y), f2bf(v.z), f2bf(v.w) };
    ((u16x4*)Y)[i] = o;
}

// ------------------------------------------------- W[K][N] f32 -> Wt[N][K] bf16
__global__ __launch_bounds__(256) void transpose_cast(
    const float* __restrict__ W, unsigned short* __restrict__ Wt, int K, int N)
{
    __shared__ float t[32][33];
    const int kb = blockIdx.x % (K >> 5);
    const int nb = blockIdx.x / (K >> 5);
    const int c = threadIdx.x & 31, r0 = threadIdx.x >> 5;
    #pragma unroll
    for (int i = 0; i < 4; i++)
        t[r0 + i * 8][c] = W[(size_t)(kb * 32 + r0 + i * 8) * N + nb * 32 + c];
    __syncthreads();
    #pragma unroll
    for (int i = 0; i < 4; i++)
        Wt[(size_t)(nb * 32 + r0 + i * 8) * K + kb * 32 + c] = f2bf(t[c][r0 + i * 8]);
}

// ---------------------------------------------------------------- GEMM (m97)
// C[m][n] = sum_k A[m][k] * Bt[n][k] + bias[n], 128x128 tile, BK=32, 4 waves.
// EPI: 0 = bf16 out; 1 = V-transposed bf16 ([B*H][64][1024]); 2 = relu bf16;
//      3 = f32 out = resid + C
template<int EPI>
__global__ __launch_bounds__(256) void gemm_bt(
    const unsigned short* __restrict__ A, const unsigned short* __restrict__ Bt,
    const float* __restrict__ bias, void* __restrict__ outp,
    const float* __restrict__ resid, int M, int N, int K)
{
    __shared__ unsigned short As[4096];   // [128][32]
    __shared__ unsigned short Bs[4096];   // [128][32]
    const int tid = threadIdx.x;
    const int lane = tid & 63, wave = tid >> 6;
    const int g = lane >> 4, q16 = lane & 15;
    const int wm = wave >> 1, wn = wave & 1;
    const int nb = N >> 7;
    const int bm = blockIdx.x / nb, bn = blockIdx.x % nb;

    const unsigned short* aSrc = A  + (size_t)(bm * 128 + (tid >> 2)) * K + (tid & 3) * 8;
    const unsigned short* bSrc = Bt + (size_t)(bn * 128 + (tid >> 2)) * K + (tid & 3) * 8;
    unsigned short* aDst = As + wave * 512;   // wave-uniform base; HW adds lane*16B
    unsigned short* bDst = Bs + wave * 512;
    const size_t rowStep = (size_t)64 * K;

    f32x4 acc[4][4] = {};

    for (int kt = 0; kt < K; kt += 32) {
        __builtin_amdgcn_global_load_lds((const AS1 unsigned int*)(aSrc + kt),           (AS3 unsigned int*)aDst,          16, 0, 0);
        __builtin_amdgcn_global_load_lds((const AS1 unsigned int*)(aSrc + rowStep + kt), (AS3 unsigned int*)(aDst + 2048), 16, 0, 0);
        __builtin_amdgcn_global_load_lds((const AS1 unsigned int*)(bSrc + kt),           (AS3 unsigned int*)bDst,          16, 0, 0);
        __builtin_amdgcn_global_load_lds((const AS1 unsigned int*)(bSrc + rowStep + kt), (AS3 unsigned int*)(bDst + 2048), 16, 0, 0);
        __syncthreads();
        short8 af[4], bfr[4];
        #pragma unroll
        for (int i = 0; i < 4; i++) af[i]  = *(const short8*)(As + (wm * 64 + i * 16 + q16) * 32 + g * 8);
        #pragma unroll
        for (int i = 0; i < 4; i++) bfr[i] = *(const short8*)(Bs + (wn * 64 + i * 16 + q16) * 32 + g * 8);
        #pragma unroll
        for (int mf = 0; mf < 4; mf++)
            #pragma unroll
            for (int nf = 0; nf < 4; nf++)
                acc[mf][nf] = __builtin_amdgcn_mfma_f32_16x16x32_bf16(af[mf], bfr[nf], acc[mf][nf], 0, 0, 0);
        __syncthreads();
    }

    const int row0 = bm * 128 + wm * 64;
    const int col0 = bn * 128 + wn * 64;
    #pragma unroll
    for (int nf = 0; nf < 4; nf++) {
        const int col = col0 + nf * 16 + q16;
        const float bv = bias[col];
        #pragma unroll
        for (int mf = 0; mf < 4; mf++) {
            const int rbase = row0 + mf * 16 + g * 4;
            #pragma unroll
            for (int r = 0; r < 4; r++) {
                const int row = rbase + r;
                const float v = acc[mf][nf][r] + bv;
                if constexpr (EPI == 0) {
                    ((unsigned short*)outp)[(size_t)row * N + col] = f2bf(v);
                } else if constexpr (EPI == 1) {
                    const int bI = row >> 10, lk = row & 1023, hh = col >> 6, dd = col & 63;
                    ((unsigned short*)outp)[((size_t)(bI * 16 + hh) * 64 + dd) * 1024 + lk] = f2bf(v);
                } else if constexpr (EPI == 2) {
                    ((unsigned short*)outp)[(size_t)row * N + col] = f2bf(v > 0.f ? v : 0.f);
                } else {
                    ((float*)outp)[(size_t)row * N + col] = resid[(size_t)row * N + col] + v;
                }
            }
        }
    }
}

// ------------------------------------------------------------- attention PV
// Per block: one (b,h,128-q tile); per wave: 32 q rows, full k sweep.
// S^T = mfma(K,Q); P = exp(S*scale) (scores are small: max-free is safe);
// shuffle P^T (C-layout) into the PV B-fragment layout; O^T += mfma(V^T, P^T).
__global__ __launch_bounds__(256) void att_pv(
    const unsigned short* __restrict__ Q, const unsigned short* __restrict__ Kb,
    const unsigned short* __restrict__ Vt, unsigned short* __restrict__ O,
    float* __restrict__ LINV)
{
    const int tid = threadIdx.x;
    const int lane = tid & 63, wave = tid >> 6;
    const int g = lane >> 4, q16 = lane & 15;
    const int qblk = blockIdx.x & 7;
    const int bh = blockIdx.x >> 3;
    const int b = bh >> 4, h = bh & 15;
    const int qbase = qblk * 128 + wave * 32;

    short8 qf[2][2];
    #pragma unroll
    for (int nf = 0; nf < 2; nf++)
        #pragma unroll
        for (int ds = 0; ds < 2; ds++)
            qf[nf][ds] = *(const short8*)(Q + (size_t)(b * 1024 + qbase + nf * 16 + q16) * 1024 + h * 64 + ds * 32 + g * 8);

    f32x4 oacc[4][2] = {};
    float lsum[2] = {0.f, 0.f};

    for (int kc = 0; kc < 1024; kc += 32) {
        short8 kf[2][2];
        #pragma unroll
        for (int kt = 0; kt < 2; kt++)
            #pragma unroll
            for (int ds = 0; ds < 2; ds++)
                kf[kt][ds] = *(const short8*)(Kb + (size_t)(b * 1024 + kc + kt * 16 + q16) * 1024 + h * 64 + ds * 32 + g * 8);
        f32x4 sacc[2][2] = {};
        #pragma unroll
        for (int kt = 0; kt < 2; kt++)
            #pragma unroll
            for (int nf = 0; nf < 2; nf++) {
                sacc[kt][nf] = __builtin_amdgcn_mfma_f32_16x16x32_bf16(kf[kt][0], qf[nf][0], sacc[kt][nf], 0, 0, 0);
                sacc[kt][nf] = __builtin_amdgcn_mfma_f32_16x16x32_bf16(kf[kt][1], qf[nf][1], sacc[kt][nf], 0, 0, 0);
            }
        // lane holds S^T[k = kc + kt*16 + 4g + r][q = qbase + nf*16 + q16]
        float ps[2][2][4];
        #pragma unroll
        for (int kt = 0; kt < 2; kt++)
            #pragma unroll
            for (int nf = 0; nf < 2; nf++)
                #pragma unroll
                for (int r = 0; r < 4; r++)
                    ps[kt][nf][r] = __expf(sacc[kt][nf][r] * 0.125f);
        #pragma unroll
        for (int nf = 0; nf < 2; nf++) {
            float t = ps[0][nf][0] + ps[0][nf][1] + ps[0][nf][2] + ps[0][nf][3]
                    + ps[1][nf][0] + ps[1][nf][1] + ps[1][nf][2] + ps[1][nf][3];
            t += __shfl_xor(t, 16);
            t += __shfl_xor(t, 32);
            lsum[nf] += t;
        }
        // shuffle into PV B-fragment: element j of lane (g,q) = P^T[kc+8g+j][q]
        short8 pbf[2];
        #pragma unroll
        for (int nf = 0; nf < 2; nf++) {
            #pragma unroll
            for (int j = 0; j < 8; j++) {
                const int srcl = (((g & 1) * 2 + (j >> 2)) << 4) | q16;
                const float vA = __shfl(ps[0][nf][j & 3], srcl);
                const float vB = __shfl(ps[1][nf][j & 3], srcl);
                pbf[nf][j] = (short)f2bf(g >= 2 ? vB : vA);
            }
        }
        short8 vf[4];
        #pragma unroll
        for (int mf = 0; mf < 4; mf++)
            vf[mf] = *(const short8*)(Vt + (size_t)(bh * 64 + mf * 16 + q16) * 1024 + kc + g * 8);
        #pragma unroll
        for (int mf = 0; mf < 4; mf++)
            #pragma unroll
            for (int nf = 0; nf < 2; nf++)
                oacc[mf][nf] = __builtin_amdgcn_mfma_f32_16x16x32_bf16(vf[mf], pbf[nf], oacc[mf][nf], 0, 0, 0);
    }
    // normalize + write O (bf16 [4096][1024], col = h*64+d), stash 1/l
    #pragma unroll
    for (int nf = 0; nf < 2; nf++) {
        const float inv = 1.0f / lsum[nf];
        if (g == 0) LINV[(size_t)bh * 1024 + qbase + nf * 16 + q16] = inv;
        #pragma unroll
        for (int mf = 0; mf < 4; mf++) {
            u16x4 o;
            #pragma unroll
            for (int r = 0; r < 4; r++) o[r] = f2bf(oacc[mf][nf][r] * inv);
            *(u16x4*)(O + (size_t)(b * 1024 + qbase + nf * 16 + q16) * 1024 + h * 64 + mf * 16 + g * 4) = o;
        }
    }
}

// ------------------------------------------------- head-averaged attn output
// Block: (b, 64-q tile, 256-k tile); wave: 64 k. Loops all 16 heads,
// recomputes S with stored 1/l, accumulates mean prob, writes f32.
__global__ __launch_bounds__(256) void att_mean(
    const unsigned short* __restrict__ Q, const unsigned short* __restrict__ Kb,
    const float* __restrict__ LINV, float* __restrict__ out1)
{
    const int tid = threadIdx.x;
    const int lane = tid & 63, wave = tid >> 6;
    const int g = lane >> 4, q16 = lane & 15;
    const int kb = blockIdx.x & 3;
    const int qb = (blockIdx.x >> 2) & 15;
    const int b = blockIdx.x >> 6;
    const int qbase = qb * 64;
    const int kbase = kb * 256 + wave * 64;

    f32x4 facc[4][4] = {};
    for (int h = 0; h < 16; h++) {
        short8 qf[4][2], kf[4][2];
        #pragma unroll
        for (int mf = 0; mf < 4; mf++)
            #pragma unroll
            for (int ds = 0; ds < 2; ds++)
                qf[mf][ds] = *(const short8*)(Q + (size_t)(b * 1024 + qbase + mf * 16 + q16) * 1024 + h * 64 + ds * 32 + g * 8);
        #pragma unroll
        for (int nf = 0; nf < 4; nf++)
            #pragma unroll
            for (int ds = 0; ds < 2; ds++)
                kf[nf][ds] = *(const short8*)(Kb + (size_t)(b * 1024 + kbase + nf * 16 + q16) * 1024 + h * 64 + ds * 32 + g * 8);
        const float* lp = LINV + (size_t)(b * 16 + h) * 1024 + qbase;
        float li[4][4];
        #pragma unroll
        for (int mf = 0; mf < 4; mf++)
            #pragma unroll
            for (int r = 0; r < 4; r++) li[mf][r] = lp[mf * 16 + g * 4 + r];
        #pragma unroll
        for (int nf = 0; nf < 4; nf++) {
            f32x4 sacc[4] = {};
            #pragma unroll
            for (int mf = 0; mf < 4; mf++) {
                sacc[mf] = __builtin_amdgcn_mfma_f32_16x16x32_bf16(qf[mf][0], kf[nf][0], sacc[mf], 0, 0, 0);
                sacc[mf] = __builtin_amdgcn_mfma_f32_16x16x32_bf16(qf[mf][1], kf[nf][1], sacc[mf], 0, 0, 0);
            }
            #pragma unroll
            for (int mf = 0; mf < 4; mf++)
                #pragma unroll
                for (int r = 0; r < 4; r++)
                    facc[mf][nf][r] += __expf(sacc[mf][r] * 0.125f) * li[mf][r];
        }
    }
    #pragma unroll
    for (int mf = 0; mf < 4; mf++)
        #pragma unroll
        for (int nf = 0; nf < 4; nf++)
            #pragma unroll
            for (int r = 0; r < 4; r++)
                out1[(size_t)(b * 1024 + qbase + mf * 16 + g * 4 + r) * 1024 + kbase + nf * 16 + q16]
                    = facc[mf][nf][r] * 0.0625f;
}

// ---------------------------------------------------------------- launcher
extern "C" void kernel_launch(void* const* d_in, const int* in_sizes, int n_in,
                              void* d_out, int out_size, void* d_ws, size_t ws_size,
                              hipStream_t stream)
{
    (void)in_sizes; (void)n_in; (void)out_size; (void)ws_size;
    const float* tgt  = (const float*)d_in[0];
    const float* mem  = (const float*)d_in[1];
    const float* ln1g = (const float*)d_in[2];
    const float* ln1b = (const float*)d_in[3];
    const float* wq   = (const float*)d_in[4];
    const float* bq   = (const float*)d_in[5];
    const float* wk   = (const float*)d_in[6];
    const float* bk   = (const float*)d_in[7];
    const float* wv   = (const float*)d_in[8];
    const float* bv   = (const float*)d_in[9];
    const float* wo   = (const float*)d_in[10];
    const float* bo   = (const float*)d_in[11];
    const float* ln3g = (const float*)d_in[12];
    const float* ln3b = (const float*)d_in[13];
    const float* w1   = (const float*)d_in[14];
    const float* b1   = (const float*)d_in[15];
    const float* w2   = (const float*)d_in[16];
    const float* b2   = (const float*)d_in[17];

    char* ws = (char*)d_ws;
    unsigned short* XA  = (unsigned short*)(ws);                  // 8 MB (t2, later t3)
    unsigned short* M16 = (unsigned short*)(ws + ((size_t)8  << 20));
    unsigned short* WQT = (unsigned short*)(ws + ((size_t)16 << 20));
    unsigned short* WKT = (unsigned short*)(ws + ((size_t)18 << 20));
    unsigned short* WVT = (unsigned short*)(ws + ((size_t)20 << 20));
    unsigned short* WOT = (unsigned short*)(ws + ((size_t)22 << 20));
    unsigned short* W1T = (unsigned short*)(ws + ((size_t)24 << 20)); // 8 MB
    unsigned short* W2T = (unsigned short*)(ws + ((size_t)32 << 20)); // 8 MB
    unsigned short* Qb  = (unsigned short*)(ws + ((size_t)40 << 20));
    unsigned short* Kb  = (unsigned short*)(ws + ((size_t)48 << 20));
    unsigned short* Vt  = (unsigned short*)(ws + ((size_t)56 << 20));
    unsigned short* O16 = (unsigned short*)(ws + ((size_t)64 << 20));
    unsigned short* H16 = (unsigned short*)(ws + ((size_t)72 << 20)); // 32 MB
    float*          LNV = (float*)(ws + ((size_t)104 << 20));         // 256 KB
    float* xout = (float*)d_out;                       // x then x+ffn [4096][1024]
    float* attn = xout + (size_t)4 * 1024 * 1024;      // [4][1024][1024]

    ln_to_bf16<<<4096, 256, 0, stream>>>(tgt, ln1g, ln1b, XA);
    cast_bf16<<<4096, 256, 0, stream>>>(mem, M16, 1024 * 1024);
    transpose_cast<<<32 * 32,  256, 0, stream>>>(wq, WQT, 1024, 1024);
    transpose_cast<<<32 * 32,  256, 0, stream>>>(wk, WKT, 1024, 1024);
    transpose_cast<<<32 * 32,  256, 0, stream>>>(wv, WVT, 1024, 1024);
    transpose_cast<<<32 * 32,  256, 0, stream>>>(wo, WOT, 1024, 1024);
    transpose_cast<<<32 * 128, 256, 0, stream>>>(w1, W1T, 1024, 4096);
    transpose_cast<<<128 * 32, 256, 0, stream>>>(w2, W2T, 4096, 1024);

    gemm_bt<0><<<32 * 8, 256, 0, stream>>>(XA,  WQT, bq, Qb, nullptr, 4096, 1024, 1024);
    gemm_bt<0><<<32 * 8, 256, 0, stream>>>(M16, WKT, bk, Kb, nullptr, 4096, 1024, 1024);
    gemm_bt<1><<<32 * 8, 256, 0, stream>>>(M16, WVT, bv, Vt, nullptr, 4096, 1024, 1024);

    att_pv<<<512, 256, 0, stream>>>(Qb, Kb, Vt, O16, LNV);
    att_mean<<<256, 256, 0, stream>>>(Qb, Kb, LNV, attn);

    gemm_bt<3><<<32 * 8, 256, 0, stream>>>(O16, WOT, bo, xout, tgt, 4096, 1024, 1024);
    ln_to_bf16<<<4096, 256, 0, stream>>>(xout, ln3g, ln3b, XA);
    gemm_bt<2><<<32 * 32, 256, 0, stream>>>(XA, W1T, b1, H16, nullptr, 4096, 4096, 1024);
    gemm_bt<3><<<32 * 8, 256, 0, stream>>>(H16, W2T, b2, xout, xout, 4096, 1024, 4096);
}

// Round 2
// 392.045 us; speedup vs baseline: 1.0886x; 1.0886x over previous
//
#include <hip/hip_runtime.h>

using short8 = __attribute__((ext_vector_type(8))) short;          // 8 bf16 (4 VGPR)
using f32x4  = __attribute__((ext_vector_type(4))) float;          // MFMA acc
using u16x4  = __attribute__((ext_vector_type(4))) unsigned short; // 8B bf16 store

#define AS1 __attribute__((address_space(1)))
#define AS3 __attribute__((address_space(3)))

__device__ __forceinline__ unsigned short f2bf(float f) {
    unsigned u = __builtin_bit_cast(unsigned, f);
    u += 0x7fffu + ((u >> 16) & 1u);           // RNE
    return (unsigned short)(u >> 16);
}

// ---------------------------------------------------------------- LN -> bf16
__global__ __launch_bounds__(256) void ln_to_bf16(
    const float* __restrict__ X, const float* __restrict__ gw,
    const float* __restrict__ bw, unsigned short* __restrict__ Y)
{
    const int row = blockIdx.x;
    const int tid = threadIdx.x;
    const float4 v = *(const float4*)(X + (size_t)row * 1024 + tid * 4);
    float s  = v.x + v.y + v.z + v.w;
    float s2 = v.x*v.x + v.y*v.y + v.z*v.z + v.w*v.w;
    #pragma unroll
    for (int off = 1; off < 64; off <<= 1) {
        s  += __shfl_xor(s,  off);
        s2 += __shfl_xor(s2, off);
    }
    __shared__ float rs[4], rq[4];
    if ((tid & 63) == 0) { rs[tid >> 6] = s; rq[tid >> 6] = s2; }
    __syncthreads();
    s  = rs[0] + rs[1] + rs[2] + rs[3];
    s2 = rq[0] + rq[1] + rq[2] + rq[3];
    const float mean = s * (1.f / 1024.f);
    const float var  = s2 * (1.f / 1024.f) - mean * mean;
    const float rstd = rsqrtf(var + 1e-5f);
    const float4 gv = *(const float4*)(gw + tid * 4);
    const float4 bv = *(const float4*)(bw + tid * 4);
    u16x4 o;
    o[0] = f2bf((v.x - mean) * rstd * gv.x + bv.x);
    o[1] = f2bf((v.y - mean) * rstd * gv.y + bv.y);
    o[2] = f2bf((v.z - mean) * rstd * gv.z + bv.z);
    o[3] = f2bf((v.w - mean) * rstd * gv.w + bv.w);
    *(u16x4*)(Y + (size_t)row * 1024 + tid * 4) = o;
}

// ---------------------------------------------------------------- f32 -> bf16
__global__ __launch_bounds__(256) void cast_bf16(
    const float* __restrict__ X, unsigned short* __restrict__ Y, int n4)
{
    int i = blockIdx.x * 256 + threadIdx.x;
    if (i >= n4) return;
    float4 v = ((const float4*)X)[i];
    u16x4 o = { f2bf(v.x), f2bf(v.y), f2bf(v.z), f2bf(v.w) };
    ((u16x4*)Y)[i] = o;
}

// ------------------------------------------------- W[K][N] f32 -> Wt[N][K] bf16
__global__ __launch_bounds__(256) void transpose_cast(
    const float* __restrict__ W, unsigned short* __restrict__ Wt, int K, int N)
{
    __shared__ float t[32][33];
    const int kb = blockIdx.x % (K >> 5);
    const int nb = blockIdx.x / (K >> 5);
    const int c = threadIdx.x & 31, r0 = threadIdx.x >> 5;
    #pragma unroll
    for (int i = 0; i < 4; i++)
        t[r0 + i * 8][c] = W[(size_t)(kb * 32 + r0 + i * 8) * N + nb * 32 + c];
    __syncthreads();
    #pragma unroll
    for (int i = 0; i < 4; i++)
        Wt[(size_t)(nb * 32 + r0 + i * 8) * K + kb * 32 + c] = f2bf(t[c][r0 + i * 8]);
}

// ---------------------------------------------------------------- GEMM (m97)
// C[m][n] = sum_k A[m][k] * Bt[n][k] + bias[n], BM=128 x BN tile, BK=32, 4 waves.
// BN=128: wave 64x64 (4x4 frags). BN=64: wave 64x32 (4x2 frags), grid 2x denser.
// EPI: 0 = bf16 out; 1 = V-transposed bf16 ([B*H][64][1024]); 2 = relu bf16;
//      3 = f32 out = resid + C; 4 = fused KV (col<1024 -> Kb linear, else Vt transposed)
template<int EPI, int BN>
__global__ __launch_bounds__(256) void gemm_bt(
    const unsigned short* __restrict__ A, const unsigned short* __restrict__ Bt,
    const float* __restrict__ bias, const float* __restrict__ bias2,
    void* __restrict__ outp, void* __restrict__ outp2,
    const float* __restrict__ resid, int M, int N, int K)
{
    constexpr int NF = BN / 32;             // frags per wave in N
    __shared__ unsigned short As[4096];     // [128][32]
    __shared__ unsigned short Bs[BN * 32];  // [BN][32]
    const int tid = threadIdx.x;
    const int lane = tid & 63, wave = tid >> 6;
    const int g = lane >> 4, q16 = lane & 15;
    const int wm = wave >> 1, wn = wave & 1;
    const int nb = N / BN;
    const int bm = blockIdx.x / nb, bn = blockIdx.x % nb;

    const unsigned short* aSrc = A  + (size_t)(bm * 128 + (tid >> 2)) * K + (tid & 3) * 8;
    const unsigned short* bSrc = Bt + (size_t)(bn * BN  + (tid >> 2)) * K + (tid & 3) * 8;
    unsigned short* aDst = As + wave * 512;   // wave-uniform base; HW adds lane*16B
    unsigned short* bDst = Bs + wave * 512;
    const size_t rowStep = (size_t)64 * K;

    f32x4 acc[4][NF] = {};

    for (int kt = 0; kt < K; kt += 32) {
        __builtin_amdgcn_global_load_lds((const AS1 unsigned int*)(aSrc + kt),           (AS3 unsigned int*)aDst,          16, 0, 0);
        __builtin_amdgcn_global_load_lds((const AS1 unsigned int*)(aSrc + rowStep + kt), (AS3 unsigned int*)(aDst + 2048), 16, 0, 0);
        __builtin_amdgcn_global_load_lds((const AS1 unsigned int*)(bSrc + kt),           (AS3 unsigned int*)bDst,          16, 0, 0);
        if constexpr (BN == 128)
            __builtin_amdgcn_global_load_lds((const AS1 unsigned int*)(bSrc + rowStep + kt), (AS3 unsigned int*)(bDst + 2048), 16, 0, 0);
        __syncthreads();
        short8 af[4], bfr[NF];
        #pragma unroll
        for (int i = 0; i < 4; i++)  af[i]  = *(const short8*)(As + (wm * 64 + i * 16 + q16) * 32 + g * 8);
        #pragma unroll
        for (int i = 0; i < NF; i++) bfr[i] = *(const short8*)(Bs + (wn * (BN / 2) + i * 16 + q16) * 32 + g * 8);
        #pragma unroll
        for (int mf = 0; mf < 4; mf++)
            #pragma unroll
            for (int nf = 0; nf < NF; nf++)
                acc[mf][nf] = __builtin_amdgcn_mfma_f32_16x16x32_bf16(af[mf], bfr[nf], acc[mf][nf], 0, 0, 0);
        __syncthreads();
    }

    const int row0 = bm * 128 + wm * 64;
    const int col0 = bn * BN + wn * (BN / 2);
    const bool isV = (EPI == 4) && (bn * BN >= 1024);   // KV-fusion: whole block uniform
    #pragma unroll
    for (int nf = 0; nf < NF; nf++) {
        const int col = col0 + nf * 16 + q16;
        const float bv = (EPI == 4 && isV) ? bias2[col - 1024] : bias[col];
        #pragma unroll
        for (int mf = 0; mf < 4; mf++) {
            const int rbase = row0 + mf * 16 + g * 4;
            #pragma unroll
            for (int r = 0; r < 4; r++) {
                const int row = rbase + r;
                const float v = acc[mf][nf][r] + bv;
                if constexpr (EPI == 0) {
                    ((unsigned short*)outp)[(size_t)row * N + col] = f2bf(v);
                } else if constexpr (EPI == 1) {
                    const int bI = row >> 10, lk = row & 1023, hh = col >> 6, dd = col & 63;
                    ((unsigned short*)outp)[((size_t)(bI * 16 + hh) * 64 + dd) * 1024 + lk] = f2bf(v);
                } else if constexpr (EPI == 2) {
                    ((unsigned short*)outp)[(size_t)row * N + col] = f2bf(v > 0.f ? v : 0.f);
                } else if constexpr (EPI == 3) {
                    ((float*)outp)[(size_t)row * N + col] = resid[(size_t)row * N + col] + v;
                } else {  // EPI == 4: fused K/V projection, N==2048
                    if (!isV) {
                        ((unsigned short*)outp)[(size_t)row * 1024 + col] = f2bf(v);
                    } else {
                        const int cc = col - 1024;
                        const int bI = row >> 10, lk = row & 1023, hh = cc >> 6, dd = cc & 63;
                        ((unsigned short*)outp2)[((size_t)(bI * 16 + hh) * 64 + dd) * 1024 + lk] = f2bf(v);
                    }
                }
            }
        }
    }
}

// ------------------------------------------------------------- attention PV
// Per block: one (b,h,128-q tile); per wave: 32 q rows, full k sweep.
// S^T = mfma(K,Q); P = exp(S*scale) (scores are small: max-free is safe);
// shuffle P^T (C-layout) into the PV B-fragment layout; O^T += mfma(V^T, P^T).
__global__ __launch_bounds__(256) void att_pv(
    const unsigned short* __restrict__ Q, const unsigned short* __restrict__ Kb,
    const unsigned short* __restrict__ Vt, unsigned short* __restrict__ O,
    float* __restrict__ LINV)
{
    const int tid = threadIdx.x;
    const int lane = tid & 63, wave = tid >> 6;
    const int g = lane >> 4, q16 = lane & 15;
    const int qblk = blockIdx.x & 7;
    const int bh = blockIdx.x >> 3;
    const int b = bh >> 4, h = bh & 15;
    const int qbase = qblk * 128 + wave * 32;

    short8 qf[2][2];
    #pragma unroll
    for (int nf = 0; nf < 2; nf++)
        #pragma unroll
        for (int ds = 0; ds < 2; ds++)
            qf[nf][ds] = *(const short8*)(Q + (size_t)(b * 1024 + qbase + nf * 16 + q16) * 1024 + h * 64 + ds * 32 + g * 8);

    f32x4 oacc[4][2] = {};
    float lsum[2] = {0.f, 0.f};

    for (int kc = 0; kc < 1024; kc += 32) {
        short8 kf[2][2];
        #pragma unroll
        for (int kt = 0; kt < 2; kt++)
            #pragma unroll
            for (int ds = 0; ds < 2; ds++)
                kf[kt][ds] = *(const short8*)(Kb + (size_t)(b * 1024 + kc + kt * 16 + q16) * 1024 + h * 64 + ds * 32 + g * 8);
        f32x4 sacc[2][2] = {};
        #pragma unroll
        for (int kt = 0; kt < 2; kt++)
            #pragma unroll
            for (int nf = 0; nf < 2; nf++) {
                sacc[kt][nf] = __builtin_amdgcn_mfma_f32_16x16x32_bf16(kf[kt][0], qf[nf][0], sacc[kt][nf], 0, 0, 0);
                sacc[kt][nf] = __builtin_amdgcn_mfma_f32_16x16x32_bf16(kf[kt][1], qf[nf][1], sacc[kt][nf], 0, 0, 0);
            }
        // lane holds S^T[k = kc + kt*16 + 4g + r][q = qbase + nf*16 + q16]
        float ps[2][2][4];
        #pragma unroll
        for (int kt = 0; kt < 2; kt++)
            #pragma unroll
            for (int nf = 0; nf < 2; nf++)
                #pragma unroll
                for (int r = 0; r < 4; r++)
                    ps[kt][nf][r] = __expf(sacc[kt][nf][r] * 0.125f);
        #pragma unroll
        for (int nf = 0; nf < 2; nf++) {
            float t = ps[0][nf][0] + ps[0][nf][1] + ps[0][nf][2] + ps[0][nf][3]
                    + ps[1][nf][0] + ps[1][nf][1] + ps[1][nf][2] + ps[1][nf][3];
            t += __shfl_xor(t, 16);
            t += __shfl_xor(t, 32);
            lsum[nf] += t;
        }
        // shuffle into PV B-fragment: element j of lane (g,q) = P^T[kc+8g+j][q]
        short8 pbf[2];
        #pragma unroll
        for (int nf = 0; nf < 2; nf++) {
            #pragma unroll
            for (int j = 0; j < 8; j++) {
                const int srcl = (((g & 1) * 2 + (j >> 2)) << 4) | q16;
                const float vA = __shfl(ps[0][nf][j & 3], srcl);
                const float vB = __shfl(ps[1][nf][j & 3], srcl);
                pbf[nf][j] = (short)f2bf(g >= 2 ? vB : vA);
            }
        }
        short8 vf[4];
        #pragma unroll
        for (int mf = 0; mf < 4; mf++)
            vf[mf] = *(const short8*)(Vt + (size_t)(bh * 64 + mf * 16 + q16) * 1024 + kc + g * 8);
        #pragma unroll
        for (int mf = 0; mf < 4; mf++)
            #pragma unroll
            for (int nf = 0; nf < 2; nf++)
                oacc[mf][nf] = __builtin_amdgcn_mfma_f32_16x16x32_bf16(vf[mf], pbf[nf], oacc[mf][nf], 0, 0, 0);
    }
    // normalize + write O (bf16 [4096][1024], col = h*64+d), stash 1/l
    #pragma unroll
    for (int nf = 0; nf < 2; nf++) {
        const float inv = 1.0f / lsum[nf];
        if (g == 0) LINV[(size_t)bh * 1024 + qbase + nf * 16 + q16] = inv;
        #pragma unroll
        for (int mf = 0; mf < 4; mf++) {
            u16x4 o;
            #pragma unroll
            for (int r = 0; r < 4; r++) o[r] = f2bf(oacc[mf][nf][r] * inv);
            *(u16x4*)(O + (size_t)(b * 1024 + qbase + nf * 16 + q16) * 1024 + h * 64 + mf * 16 + g * 4) = o;
        }
    }
}

// ------------------------------------------------- head-averaged attn output
// Block: (b, 64-q tile, 128-k tile); wave: 32 k. Loops all 16 heads,
// recomputes S with stored 1/l, accumulates mean prob, writes f32. grid=512.
__global__ __launch_bounds__(256) void att_mean(
    const unsigned short* __restrict__ Q, const unsigned short* __restrict__ Kb,
    const float* __restrict__ LINV, float* __restrict__ out1)
{
    const int tid = threadIdx.x;
    const int lane = tid & 63, wave = tid >> 6;
    const int g = lane >> 4, q16 = lane & 15;
    const int kb = blockIdx.x & 7;
    const int qb = (blockIdx.x >> 3) & 15;
    const int b = blockIdx.x >> 7;
    const int qbase = qb * 64;
    const int kbase = kb * 128 + wave * 32;

    f32x4 facc[4][2] = {};
    for (int h = 0; h < 16; h++) {
        short8 qf[4][2], kf[2][2];
        #pragma unroll
        for (int mf = 0; mf < 4; mf++)
            #pragma unroll
            for (int ds = 0; ds < 2; ds++)
                qf[mf][ds] = *(const short8*)(Q + (size_t)(b * 1024 + qbase + mf * 16 + q16) * 1024 + h * 64 + ds * 32 + g * 8);
        #pragma unroll
        for (int nf = 0; nf < 2; nf++)
            #pragma unroll
            for (int ds = 0; ds < 2; ds++)
                kf[nf][ds] = *(const short8*)(Kb + (size_t)(b * 1024 + kbase + nf * 16 + q16) * 1024 + h * 64 + ds * 32 + g * 8);
        const float* lp = LINV + (size_t)(b * 16 + h) * 1024 + qbase;
        float li[4][4];
        #pragma unroll
        for (int mf = 0; mf < 4; mf++)
            #pragma unroll
            for (int r = 0; r < 4; r++) li[mf][r] = lp[mf * 16 + g * 4 + r];
        #pragma unroll
        for (int nf = 0; nf < 2; nf++) {
            f32x4 sacc[4] = {};
            #pragma unroll
            for (int mf = 0; mf < 4; mf++) {
                sacc[mf] = __builtin_amdgcn_mfma_f32_16x16x32_bf16(qf[mf][0], kf[nf][0], sacc[mf], 0, 0, 0);
                sacc[mf] = __builtin_amdgcn_mfma_f32_16x16x32_bf16(qf[mf][1], kf[nf][1], sacc[mf], 0, 0, 0);
            }
            #pragma unroll
            for (int mf = 0; mf < 4; mf++)
                #pragma unroll
                for (int r = 0; r < 4; r++)
                    facc[mf][nf][r] += __expf(sacc[mf][r] * 0.125f) * li[mf][r];
        }
    }
    #pragma unroll
    for (int mf = 0; mf < 4; mf++)
        #pragma unroll
        for (int nf = 0; nf < 2; nf++)
            #pragma unroll
            for (int r = 0; r < 4; r++)
                out1[(size_t)(b * 1024 + qbase + mf * 16 + g * 4 + r) * 1024 + kbase + nf * 16 + q16]
                    = facc[mf][nf][r] * 0.0625f;
}

// ---------------------------------------------------------------- launcher
extern "C" void kernel_launch(void* const* d_in, const int* in_sizes, int n_in,
                              void* d_out, int out_size, void* d_ws, size_t ws_size,
                              hipStream_t stream)
{
    (void)in_sizes; (void)n_in; (void)out_size; (void)ws_size;
    const float* tgt  = (const float*)d_in[0];
    const float* mem  = (const float*)d_in[1];
    const float* ln1g = (const float*)d_in[2];
    const float* ln1b = (const float*)d_in[3];
    const float* wq   = (const float*)d_in[4];
    const float* bq   = (const float*)d_in[5];
    const float* wk   = (const float*)d_in[6];
    const float* bk   = (const float*)d_in[7];
    const float* wv   = (const float*)d_in[8];
    const float* bv   = (const float*)d_in[9];
    const float* wo   = (const float*)d_in[10];
    const float* bo   = (const float*)d_in[11];
    const float* ln3g = (const float*)d_in[12];
    const float* ln3b = (const float*)d_in[13];
    const float* w1   = (const float*)d_in[14];
    const float* b1   = (const float*)d_in[15];
    const float* w2   = (const float*)d_in[16];
    const float* b2   = (const float*)d_in[17];

    char* ws = (char*)d_ws;
    unsigned short* XA  = (unsigned short*)(ws);                  // 8 MB (t2, later t3)
    unsigned short* M16 = (unsigned short*)(ws + ((size_t)8  << 20));
    unsigned short* WQT = (unsigned short*)(ws + ((size_t)16 << 20));
    unsigned short* WKT = (unsigned short*)(ws + ((size_t)18 << 20)); // [WKT;WVT] = fused 2048xK
    unsigned short* WVT = (unsigned short*)(ws + ((size_t)20 << 20));
    unsigned short* WOT = (unsigned short*)(ws + ((size_t)22 << 20));
    unsigned short* W1T = (unsigned short*)(ws + ((size_t)24 << 20)); // 8 MB
    unsigned short* W2T = (unsigned short*)(ws + ((size_t)32 << 20)); // 8 MB
    unsigned short* Qb  = (unsigned short*)(ws + ((size_t)40 << 20));
    unsigned short* Kb  = (unsigned short*)(ws + ((size_t)48 << 20));
    unsigned short* Vt  = (unsigned short*)(ws + ((size_t)56 << 20));
    unsigned short* O16 = (unsigned short*)(ws + ((size_t)64 << 20));
    unsigned short* H16 = (unsigned short*)(ws + ((size_t)72 << 20)); // 32 MB
    float*          LNV = (float*)(ws + ((size_t)104 << 20));         // 256 KB
    float* xout = (float*)d_out;                       // x then x+ffn [4096][1024]
    float* attn = xout + (size_t)4 * 1024 * 1024;      // [4][1024][1024]

    ln_to_bf16<<<4096, 256, 0, stream>>>(tgt, ln1g, ln1b, XA);
    cast_bf16<<<4096, 256, 0, stream>>>(mem, M16, 1024 * 1024);
    transpose_cast<<<32 * 32,  256, 0, stream>>>(wq, WQT, 1024, 1024);
    transpose_cast<<<32 * 32,  256, 0, stream>>>(wk, WKT, 1024, 1024);
    transpose_cast<<<32 * 32,  256, 0, stream>>>(wv, WVT, 1024, 1024);
    transpose_cast<<<32 * 32,  256, 0, stream>>>(wo, WOT, 1024, 1024);
    transpose_cast<<<32 * 128, 256, 0, stream>>>(w1, W1T, 1024, 4096);
    transpose_cast<<<128 * 32, 256, 0, stream>>>(w2, W2T, 4096, 1024);

    // Q projection: N=1024, BN=64 -> grid 512 (2 blocks/CU)
    gemm_bt<0, 64><<<32 * 16, 256, 0, stream>>>(XA, WQT, bq, nullptr, Qb, nullptr, nullptr, 4096, 1024, 1024);
    // fused K+V projection: N=2048, BN=128 -> grid 512
    gemm_bt<4, 128><<<32 * 16, 256, 0, stream>>>(M16, WKT, bk, bv, Kb, Vt, nullptr, 4096, 2048, 1024);

    att_pv<<<512, 256, 0, stream>>>(Qb, Kb, Vt, O16, LNV);
    att_mean<<<512, 256, 0, stream>>>(Qb, Kb, LNV, attn);

    // WO: N=1024, BN=64 -> grid 512
    gemm_bt<3, 64><<<32 * 16, 256, 0, stream>>>(O16, WOT, bo, nullptr, xout, nullptr, tgt, 4096, 1024, 1024);
    ln_to_bf16<<<4096, 256, 0, stream>>>(xout, ln3g, ln3b, XA);
    // FFN1: N=4096, BN=128 -> grid 1024
    gemm_bt<2, 128><<<32 * 32, 256, 0, stream>>>(XA, W1T, b1, nullptr, H16, nullptr, nullptr, 4096, 4096, 1024);
    // FFN2: N=1024, K=4096, BN=64 -> grid 512
    gemm_bt<3, 64><<<32 * 16, 256, 0, stream>>>(H16, W2T, b2, nullptr, xout, nullptr, xout, 4096, 1024, 4096);
}

// Round 3
// 360.680 us; speedup vs baseline: 1.1833x; 1.0870x over previous
//
#include <hip/hip_runtime.h>

using short8 = __attribute__((ext_vector_type(8))) short;          // 8 bf16 (4 VGPR)
using f32x4  = __attribute__((ext_vector_type(4))) float;          // MFMA acc
using u16x4  = __attribute__((ext_vector_type(4))) unsigned short; // 8B bf16 store

#define AS1 __attribute__((address_space(1)))
#define AS3 __attribute__((address_space(3)))

__device__ __forceinline__ unsigned short f2bf(float f) {
    unsigned u = __builtin_bit_cast(unsigned, f);
    u += 0x7fffu + ((u >> 16) & 1u);           // RNE
    return (unsigned short)(u >> 16);
}

// ---------------------------------------------------------------- LN -> bf16
__global__ __launch_bounds__(256) void ln_to_bf16(
    const float* __restrict__ X, const float* __restrict__ gw,
    const float* __restrict__ bw, unsigned short* __restrict__ Y)
{
    const int row = blockIdx.x;
    const int tid = threadIdx.x;
    const float4 v = *(const float4*)(X + (size_t)row * 1024 + tid * 4);
    float s  = v.x + v.y + v.z + v.w;
    float s2 = v.x*v.x + v.y*v.y + v.z*v.z + v.w*v.w;
    #pragma unroll
    for (int off = 1; off < 64; off <<= 1) {
        s  += __shfl_xor(s,  off);
        s2 += __shfl_xor(s2, off);
    }
    __shared__ float rs[4], rq[4];
    if ((tid & 63) == 0) { rs[tid >> 6] = s; rq[tid >> 6] = s2; }
    __syncthreads();
    s  = rs[0] + rs[1] + rs[2] + rs[3];
    s2 = rq[0] + rq[1] + rq[2] + rq[3];
    const float mean = s * (1.f / 1024.f);
    const float var  = s2 * (1.f / 1024.f) - mean * mean;
    const float rstd = rsqrtf(var + 1e-5f);
    const float4 gv = *(const float4*)(gw + tid * 4);
    const float4 bv = *(const float4*)(bw + tid * 4);
    u16x4 o;
    o[0] = f2bf((v.x - mean) * rstd * gv.x + bv.x);
    o[1] = f2bf((v.y - mean) * rstd * gv.y + bv.y);
    o[2] = f2bf((v.z - mean) * rstd * gv.z + bv.z);
    o[3] = f2bf((v.w - mean) * rstd * gv.w + bv.w);
    *(u16x4*)(Y + (size_t)row * 1024 + tid * 4) = o;
}

// ---------------------------------------------------------------- f32 -> bf16
__global__ __launch_bounds__(256) void cast_bf16(
    const float* __restrict__ X, unsigned short* __restrict__ Y, int n4)
{
    int i = blockIdx.x * 256 + threadIdx.x;
    if (i >= n4) return;
    float4 v = ((const float4*)X)[i];
    u16x4 o = { f2bf(v.x), f2bf(v.y), f2bf(v.z), f2bf(v.w) };
    ((u16x4*)Y)[i] = o;
}

// ------------------------------------------------- W[K][N] f32 -> Wt[N][K] bf16
__global__ __launch_bounds__(256) void transpose_cast(
    const float* __restrict__ W, unsigned short* __restrict__ Wt, int K, int N)
{
    __shared__ float t[32][33];
    const int kb = blockIdx.x % (K >> 5);
    const int nb = blockIdx.x / (K >> 5);
    const int c = threadIdx.x & 31, r0 = threadIdx.x >> 5;
    #pragma unroll
    for (int i = 0; i < 4; i++)
        t[r0 + i * 8][c] = W[(size_t)(kb * 32 + r0 + i * 8) * N + nb * 32 + c];
    __syncthreads();
    #pragma unroll
    for (int i = 0; i < 4; i++)
        Wt[(size_t)(nb * 32 + r0 + i * 8) * K + kb * 32 + c] = f2bf(t[c][r0 + i * 8]);
}

// ---------------------------- four fused 1024x1024 transposes (one launch)
__global__ __launch_bounds__(256) void transpose_cast4(
    const float* __restrict__ w0, const float* __restrict__ w1,
    const float* __restrict__ w2, const float* __restrict__ w3,
    unsigned short* __restrict__ t0, unsigned short* __restrict__ t1,
    unsigned short* __restrict__ t2, unsigned short* __restrict__ t3)
{
    __shared__ float t[32][33];
    const int which = blockIdx.x >> 10;
    const float* W = which == 0 ? w0 : which == 1 ? w1 : which == 2 ? w2 : w3;
    unsigned short* Wt = which == 0 ? t0 : which == 1 ? t1 : which == 2 ? t2 : t3;
    const int idx = blockIdx.x & 1023;
    const int kb = idx & 31, nb = idx >> 5;
    const int c = threadIdx.x & 31, r0 = threadIdx.x >> 5;
    #pragma unroll
    for (int i = 0; i < 4; i++)
        t[r0 + i * 8][c] = W[(size_t)(kb * 32 + r0 + i * 8) * 1024 + nb * 32 + c];
    __syncthreads();
    #pragma unroll
    for (int i = 0; i < 4; i++)
        Wt[(size_t)(nb * 32 + r0 + i * 8) * 1024 + kb * 32 + c] = f2bf(t[c][r0 + i * 8]);
}

// --------------------------------------------- GEMM (m97 + T3 min-2-phase dbuf)
// C[m][n] = sum_k A[m][k] * Bt[n][k] + bias[n], BM=128 x BN tile, BK=32, 4 waves.
// K-loop: STAGE(next buf) BEFORE compute(cur); single __syncthreads per step
// (its vmcnt/lgkmcnt drain covers both the prefetch and the LDS reads).
// EPI: 0 = bf16 out; 1 = V-transposed bf16 ([B*H][64][1024]); 2 = relu bf16;
//      3 = f32 out = resid + C; 4 = fused KV (col<1024 -> Kb linear, else Vt transposed)
template<int EPI, int BN>
__global__ __launch_bounds__(256) void gemm_bt(
    const unsigned short* __restrict__ A, const unsigned short* __restrict__ Bt,
    const float* __restrict__ bias, const float* __restrict__ bias2,
    void* __restrict__ outp, void* __restrict__ outp2,
    const float* __restrict__ resid, int M, int N, int K)
{
    constexpr int NF = BN / 32;                 // frags per wave in N
    constexpr int LDSH = (128 + BN) * 32;       // elems per buffer (A then B)
    __shared__ unsigned short S[2 * LDSH];      // double buffer
    const int tid = threadIdx.x;
    const int lane = tid & 63, wave = tid >> 6;
    const int g = lane >> 4, q16 = lane & 15;
    const int wm = wave >> 1, wn = wave & 1;
    const int nb = N / BN;
    const int bm = blockIdx.x / nb, bn = blockIdx.x % nb;

    const unsigned short* aSrc = A  + (size_t)(bm * 128 + (tid >> 2)) * K + (tid & 3) * 8;
    const unsigned short* bSrc = Bt + (size_t)(bn * BN  + (tid >> 2)) * K + (tid & 3) * 8;
    const size_t rowStep = (size_t)64 * K;

    f32x4 acc[4][NF] = {};

    auto STAGE = [&](int buf, int kt) {
        unsigned short* aDst = &S[buf * LDSH] + wave * 512;        // wave-uniform base
        unsigned short* bDst = &S[buf * LDSH + 4096] + wave * 512;
        __builtin_amdgcn_global_load_lds((const AS1 unsigned int*)(aSrc + kt),           (AS3 unsigned int*)aDst,          16, 0, 0);
        __builtin_amdgcn_global_load_lds((const AS1 unsigned int*)(aSrc + rowStep + kt), (AS3 unsigned int*)(aDst + 2048), 16, 0, 0);
        __builtin_amdgcn_global_load_lds((const AS1 unsigned int*)(bSrc + kt),           (AS3 unsigned int*)bDst,          16, 0, 0);
        if constexpr (BN == 128)
            __builtin_amdgcn_global_load_lds((const AS1 unsigned int*)(bSrc + rowStep + kt), (AS3 unsigned int*)(bDst + 2048), 16, 0, 0);
    };
    auto COMPUTE = [&](int buf) {
        const unsigned short* As = &S[buf * LDSH];
        const unsigned short* Bs = As + 4096;
        short8 af[4], bfr[NF];
        #pragma unroll
        for (int i = 0; i < 4; i++)  af[i]  = *(const short8*)(As + (wm * 64 + i * 16 + q16) * 32 + g * 8);
        #pragma unroll
        for (int i = 0; i < NF; i++) bfr[i] = *(const short8*)(Bs + (wn * (BN / 2) + i * 16 + q16) * 32 + g * 8);
        #pragma unroll
        for (int mf = 0; mf < 4; mf++)
            #pragma unroll
            for (int nf = 0; nf < NF; nf++)
                acc[mf][nf] = __builtin_amdgcn_mfma_f32_16x16x32_bf16(af[mf], bfr[nf], acc[mf][nf], 0, 0, 0);
    };

    STAGE(0, 0);
    __syncthreads();                 // drains vmcnt(0): buf0 ready
    int cur = 0;
    for (int kt = 32; kt < K; kt += 32) {
        STAGE(cur ^ 1, kt);          // prefetch flies under the MFMAs below
        COMPUTE(cur);
        __syncthreads();             // drain: next buf ready, cur free for overwrite
        cur ^= 1;
    }
    COMPUTE(cur);                    // last tile (no prefetch)

    const int row0 = bm * 128 + wm * 64;
    const int col0 = bn * BN + wn * (BN / 2);
    const bool isV = (EPI == 4) && (bn * BN >= 1024);   // KV-fusion: whole block uniform
    #pragma unroll
    for (int nf = 0; nf < NF; nf++) {
        const int col = col0 + nf * 16 + q16;
        const float bv = (EPI == 4 && isV) ? bias2[col - 1024] : bias[col];
        #pragma unroll
        for (int mf = 0; mf < 4; mf++) {
            const int rbase = row0 + mf * 16 + g * 4;
            #pragma unroll
            for (int r = 0; r < 4; r++) {
                const int row = rbase + r;
                const float v = acc[mf][nf][r] + bv;
                if constexpr (EPI == 0) {
                    ((unsigned short*)outp)[(size_t)row * N + col] = f2bf(v);
                } else if constexpr (EPI == 1) {
                    const int bI = row >> 10, lk = row & 1023, hh = col >> 6, dd = col & 63;
                    ((unsigned short*)outp)[((size_t)(bI * 16 + hh) * 64 + dd) * 1024 + lk] = f2bf(v);
                } else if constexpr (EPI == 2) {
                    ((unsigned short*)outp)[(size_t)row * N + col] = f2bf(v > 0.f ? v : 0.f);
                } else if constexpr (EPI == 3) {
                    ((float*)outp)[(size_t)row * N + col] = resid[(size_t)row * N + col] + v;
                } else {  // EPI == 4: fused K/V projection, N==2048
                    if (!isV) {
                        ((unsigned short*)outp)[(size_t)row * 1024 + col] = f2bf(v);
                    } else {
                        const int cc = col - 1024;
                        const int bI = row >> 10, lk = row & 1023, hh = cc >> 6, dd = cc & 63;
                        ((unsigned short*)outp2)[((size_t)(bI * 16 + hh) * 64 + dd) * 1024 + lk] = f2bf(v);
                    }
                }
            }
        }
    }
}

// ------------------------------------------------------------- attention PV
// Per block: one (b,h,128-q tile); per wave: 32 q rows, full k sweep.
// S^T = mfma(K,Q); P = exp(S*scale) (scores are small: max-free is safe);
// shuffle P^T (C-layout) into the PV B-fragment layout; O^T += mfma(V^T, P^T).
__global__ __launch_bounds__(256) void att_pv(
    const unsigned short* __restrict__ Q, const unsigned short* __restrict__ Kb,
    const unsigned short* __restrict__ Vt, unsigned short* __restrict__ O,
    float* __restrict__ LINV)
{
    const int tid = threadIdx.x;
    const int lane = tid & 63, wave = tid >> 6;
    const int g = lane >> 4, q16 = lane & 15;
    const int qblk = blockIdx.x & 7;
    const int bh = blockIdx.x >> 3;
    const int b = bh >> 4, h = bh & 15;
    const int qbase = qblk * 128 + wave * 32;

    short8 qf[2][2];
    #pragma unroll
    for (int nf = 0; nf < 2; nf++)
        #pragma unroll
        for (int ds = 0; ds < 2; ds++)
            qf[nf][ds] = *(const short8*)(Q + (size_t)(b * 1024 + qbase + nf * 16 + q16) * 1024 + h * 64 + ds * 32 + g * 8);

    f32x4 oacc[4][2] = {};
    float lsum[2] = {0.f, 0.f};

    for (int kc = 0; kc < 1024; kc += 32) {
        short8 kf[2][2];
        #pragma unroll
        for (int kt = 0; kt < 2; kt++)
            #pragma unroll
            for (int ds = 0; ds < 2; ds++)
                kf[kt][ds] = *(const short8*)(Kb + (size_t)(b * 1024 + kc + kt * 16 + q16) * 1024 + h * 64 + ds * 32 + g * 8);
        f32x4 sacc[2][2] = {};
        #pragma unroll
        for (int kt = 0; kt < 2; kt++)
            #pragma unroll
            for (int nf = 0; nf < 2; nf++) {
                sacc[kt][nf] = __builtin_amdgcn_mfma_f32_16x16x32_bf16(kf[kt][0], qf[nf][0], sacc[kt][nf], 0, 0, 0);
                sacc[kt][nf] = __builtin_amdgcn_mfma_f32_16x16x32_bf16(kf[kt][1], qf[nf][1], sacc[kt][nf], 0, 0, 0);
            }
        // lane holds S^T[k = kc + kt*16 + 4g + r][q = qbase + nf*16 + q16]
        float ps[2][2][4];
        #pragma unroll
        for (int kt = 0; kt < 2; kt++)
            #pragma unroll
            for (int nf = 0; nf < 2; nf++)
                #pragma unroll
                for (int r = 0; r < 4; r++)
                    ps[kt][nf][r] = __expf(sacc[kt][nf][r] * 0.125f);
        #pragma unroll
        for (int nf = 0; nf < 2; nf++) {
            float t = ps[0][nf][0] + ps[0][nf][1] + ps[0][nf][2] + ps[0][nf][3]
                    + ps[1][nf][0] + ps[1][nf][1] + ps[1][nf][2] + ps[1][nf][3];
            t += __shfl_xor(t, 16);
            t += __shfl_xor(t, 32);
            lsum[nf] += t;
        }
        // shuffle into PV B-fragment: element j of lane (g,q) = P^T[kc+8g+j][q]
        short8 pbf[2];
        #pragma unroll
        for (int nf = 0; nf < 2; nf++) {
            #pragma unroll
            for (int j = 0; j < 8; j++) {
                const int srcl = (((g & 1) * 2 + (j >> 2)) << 4) | q16;
                const float vA = __shfl(ps[0][nf][j & 3], srcl);
                const float vB = __shfl(ps[1][nf][j & 3], srcl);
                pbf[nf][j] = (short)f2bf(g >= 2 ? vB : vA);
            }
        }
        short8 vf[4];
        #pragma unroll
        for (int mf = 0; mf < 4; mf++)
            vf[mf] = *(const short8*)(Vt + (size_t)(bh * 64 + mf * 16 + q16) * 1024 + kc + g * 8);
        #pragma unroll
        for (int mf = 0; mf < 4; mf++)
            #pragma unroll
            for (int nf = 0; nf < 2; nf++)
                oacc[mf][nf] = __builtin_amdgcn_mfma_f32_16x16x32_bf16(vf[mf], pbf[nf], oacc[mf][nf], 0, 0, 0);
    }
    // normalize + write O (bf16 [4096][1024], col = h*64+d), stash 1/l
    #pragma unroll
    for (int nf = 0; nf < 2; nf++) {
        const float inv = 1.0f / lsum[nf];
        if (g == 0) LINV[(size_t)bh * 1024 + qbase + nf * 16 + q16] = inv;
        #pragma unroll
        for (int mf = 0; mf < 4; mf++) {
            u16x4 o;
            #pragma unroll
            for (int r = 0; r < 4; r++) o[r] = f2bf(oacc[mf][nf][r] * inv);
            *(u16x4*)(O + (size_t)(b * 1024 + qbase + nf * 16 + q16) * 1024 + h * 64 + mf * 16 + g * 4) = o;
        }
    }
}

// ------------------------------------------------- head-averaged attn output
// Block: (b, 64-q tile, 128-k tile); wave: 32 k. Loops all 16 heads,
// recomputes S with stored 1/l, accumulates mean prob, writes f32. grid=512.
__global__ __launch_bounds__(256) void att_mean(
    const unsigned short* __restrict__ Q, const unsigned short* __restrict__ Kb,
    const float* __restrict__ LINV, float* __restrict__ out1)
{
    const int tid = threadIdx.x;
    const int lane = tid & 63, wave = tid >> 6;
    const int g = lane >> 4, q16 = lane & 15;
    const int kb = blockIdx.x & 7;
    const int qb = (blockIdx.x >> 3) & 15;
    const int b = blockIdx.x >> 7;
    const int qbase = qb * 64;
    const int kbase = kb * 128 + wave * 32;

    f32x4 facc[4][2] = {};
    for (int h = 0; h < 16; h++) {
        short8 qf[4][2], kf[2][2];
        #pragma unroll
        for (int mf = 0; mf < 4; mf++)
            #pragma unroll
            for (int ds = 0; ds < 2; ds++)
                qf[mf][ds] = *(const short8*)(Q + (size_t)(b * 1024 + qbase + mf * 16 + q16) * 1024 + h * 64 + ds * 32 + g * 8);
        #pragma unroll
        for (int nf = 0; nf < 2; nf++)
            #pragma unroll
            for (int ds = 0; ds < 2; ds++)
                kf[nf][ds] = *(const short8*)(Kb + (size_t)(b * 1024 + kbase + nf * 16 + q16) * 1024 + h * 64 + ds * 32 + g * 8);
        const float* lp = LINV + (size_t)(b * 16 + h) * 1024 + qbase;
        float li[4][4];
        #pragma unroll
        for (int mf = 0; mf < 4; mf++)
            #pragma unroll
            for (int r = 0; r < 4; r++) li[mf][r] = lp[mf * 16 + g * 4 + r];
        #pragma unroll
        for (int nf = 0; nf < 2; nf++) {
            f32x4 sacc[4] = {};
            #pragma unroll
            for (int mf = 0; mf < 4; mf++) {
                sacc[mf] = __builtin_amdgcn_mfma_f32_16x16x32_bf16(qf[mf][0], kf[nf][0], sacc[mf], 0, 0, 0);
                sacc[mf] = __builtin_amdgcn_mfma_f32_16x16x32_bf16(qf[mf][1], kf[nf][1], sacc[mf], 0, 0, 0);
            }
            #pragma unroll
            for (int mf = 0; mf < 4; mf++)
                #pragma unroll
                for (int r = 0; r < 4; r++)
                    facc[mf][nf][r] += __expf(sacc[mf][r] * 0.125f) * li[mf][r];
        }
    }
    #pragma unroll
    for (int mf = 0; mf < 4; mf++)
        #pragma unroll
        for (int nf = 0; nf < 2; nf++)
            #pragma unroll
            for (int r = 0; r < 4; r++)
                out1[(size_t)(b * 1024 + qbase + mf * 16 + g * 4 + r) * 1024 + kbase + nf * 16 + q16]
                    = facc[mf][nf][r] * 0.0625f;
}

// ---------------------------------------------------------------- launcher
extern "C" void kernel_launch(void* const* d_in, const int* in_sizes, int n_in,
                              void* d_out, int out_size, void* d_ws, size_t ws_size,
                              hipStream_t stream)
{
    (void)in_sizes; (void)n_in; (void)out_size; (void)ws_size;
    const float* tgt  = (const float*)d_in[0];
    const float* mem  = (const float*)d_in[1];
    const float* ln1g = (const float*)d_in[2];
    const float* ln1b = (const float*)d_in[3];
    const float* wq   = (const float*)d_in[4];
    const float* bq   = (const float*)d_in[5];
    const float* wk   = (const float*)d_in[6];
    const float* bk   = (const float*)d_in[7];
    const float* wv   = (const float*)d_in[8];
    const float* bv   = (const float*)d_in[9];
    const float* wo   = (const float*)d_in[10];
    const float* bo   = (const float*)d_in[11];
    const float* ln3g = (const float*)d_in[12];
    const float* ln3b = (const float*)d_in[13];
    const float* w1   = (const float*)d_in[14];
    const float* b1   = (const float*)d_in[15];
    const float* w2   = (const float*)d_in[16];
    const float* b2   = (const float*)d_in[17];

    char* ws = (char*)d_ws;
    unsigned short* XA  = (unsigned short*)(ws);                  // 8 MB (t2, later t3)
    unsigned short* M16 = (unsigned short*)(ws + ((size_t)8  << 20));
    unsigned short* WQT = (unsigned short*)(ws + ((size_t)16 << 20));
    unsigned short* WKT = (unsigned short*)(ws + ((size_t)18 << 20)); // [WKT;WVT] = fused 2048xK
    unsigned short* WVT = (unsigned short*)(ws + ((size_t)20 << 20));
    unsigned short* WOT = (unsigned short*)(ws + ((size_t)22 << 20));
    unsigned short* W1T = (unsigned short*)(ws + ((size_t)24 << 20)); // 8 MB
    unsigned short* W2T = (unsigned short*)(ws + ((size_t)32 << 20)); // 8 MB
    unsigned short* Qb  = (unsigned short*)(ws + ((size_t)40 << 20));
    unsigned short* Kb  = (unsigned short*)(ws + ((size_t)48 << 20));
    unsigned short* Vt  = (unsigned short*)(ws + ((size_t)56 << 20));
    unsigned short* O16 = (unsigned short*)(ws + ((size_t)64 << 20));
    unsigned short* H16 = (unsigned short*)(ws + ((size_t)72 << 20)); // 32 MB
    float*          LNV = (float*)(ws + ((size_t)104 << 20));         // 256 KB
    float* xout = (float*)d_out;                       // x then x+ffn [4096][1024]
    float* attn = xout + (size_t)4 * 1024 * 1024;      // [4][1024][1024]

    ln_to_bf16<<<4096, 256, 0, stream>>>(tgt, ln1g, ln1b, XA);
    cast_bf16<<<4096, 256, 0, stream>>>(mem, M16, 1024 * 1024);
    transpose_cast4<<<4096, 256, 0, stream>>>(wq, wk, wv, wo, WQT, WKT, WVT, WOT);
    transpose_cast<<<32 * 128, 256, 0, stream>>>(w1, W1T, 1024, 4096);
    transpose_cast<<<128 * 32, 256, 0, stream>>>(w2, W2T, 4096, 1024);

    // Q projection: N=1024, BN=64 -> grid 512 (2 blocks/CU)
    gemm_bt<0, 64><<<32 * 16, 256, 0, stream>>>(XA, WQT, bq, nullptr, Qb, nullptr, nullptr, 4096, 1024, 1024);
    // fused K+V projection: N=2048, BN=128 -> grid 512
    gemm_bt<4, 128><<<32 * 16, 256, 0, stream>>>(M16, WKT, bk, bv, Kb, Vt, nullptr, 4096, 2048, 1024);

    att_pv<<<512, 256, 0, stream>>>(Qb, Kb, Vt, O16, LNV);
    att_mean<<<512, 256, 0, stream>>>(Qb, Kb, LNV, attn);

    // WO: N=1024, BN=64 -> grid 512
    gemm_bt<3, 64><<<32 * 16, 256, 0, stream>>>(O16, WOT, bo, nullptr, xout, nullptr, tgt, 4096, 1024, 1024);
    ln_to_bf16<<<4096, 256, 0, stream>>>(xout, ln3g, ln3b, XA);
    // FFN1: N=4096, BN=128 -> grid 1024
    gemm_bt<2, 128><<<32 * 32, 256, 0, stream>>>(XA, W1T, b1, nullptr, H16, nullptr, nullptr, 4096, 4096, 1024);
    // FFN2: N=1024, K=4096, BN=64 -> grid 512
    gemm_bt<3, 64><<<32 * 16, 256, 0, stream>>>(H16, W2T, b2, nullptr, xout, nullptr, xout, 4096, 1024, 4096);
}